// Round 5
// baseline (243.340 us; speedup 1.0000x reference)
//
#include <hip/hip_runtime.h>
#include <hip/hip_bf16.h>

using bf16x8 = __attribute__((ext_vector_type(8))) __bf16;
using f32x4  = __attribute__((ext_vector_type(4))) float;

// ============ CSR build (deterministic two-level binning, bshift=8) ============
__global__ __launch_bounds__(256) void bin_hist_k(
    const int* __restrict__ e32, const long long* __restrict__ e64,
    int* __restrict__ blockhist /*[B1][NB]*/, int E, int NB, int bshift, int chunk)
{
    __shared__ int hist[512];
    __shared__ int sflag;
    const int tid = threadIdx.x;
    if (tid < 64) {
        unsigned long long b = __ballot(e32[2 * tid + 1] != 0);
        if (tid == 0) sflag = (b == 0ULL);
    }
    for (int i = tid; i < NB; i += 256) hist[i] = 0;
    __syncthreads();
    const bool i64f = (sflag != 0);
    const int base = blockIdx.x * chunk;
    const int end  = min(base + chunk, E);
    for (int i = base + tid; i < end; i += 256) {
        int d = i64f ? (int)e64[(size_t)E + i] : e32[(size_t)E + i];
        atomicAdd(&hist[d >> bshift], 1);
    }
    __syncthreads();
    int* row = blockhist + (size_t)blockIdx.x * NB;
    for (int b = tid; b < NB; b += 256) row[b] = hist[b];
}

__global__ __launch_bounds__(256) void scanA_k(
    const int* __restrict__ blockhist, int* __restrict__ bh_ex /*[NB][B1]*/,
    int* __restrict__ btot, int NB, int B1)
{
    __shared__ int v[256];
    const int t = threadIdx.x, b = blockIdx.x;
    int x = (t < B1) ? blockhist[(size_t)t * NB + b] : 0;
    v[t] = x; __syncthreads();
    for (int off = 1; off < 256; off <<= 1) {
        int y = (t >= off) ? v[t - off] : 0;
        __syncthreads();
        v[t] += y;
        __syncthreads();
    }
    if (t < B1) bh_ex[(size_t)b * B1 + t] = v[t] - x;
    if (t == 255) btot[b] = v[255];
}

__global__ __launch_bounds__(256) void scanB_k(
    const int* __restrict__ btot, int* __restrict__ bucket_base,
    int* __restrict__ row_ptr, int NB, int N)
{
    __shared__ int ts[256];
    const int t = threadIdx.x;
    int v[4], s = 0;
#pragma unroll
    for (int j = 0; j < 4; ++j) { int i = t * 4 + j; v[j] = (i < NB) ? btot[i] : 0; s += v[j]; }
    ts[t] = s; __syncthreads();
    for (int off = 1; off < 256; off <<= 1) {
        int x = (t >= off) ? ts[t - off] : 0;
        __syncthreads();
        ts[t] += x;
        __syncthreads();
    }
    int base = ts[t] - s;
#pragma unroll
    for (int j = 0; j < 4; ++j) {
        int i = t * 4 + j;
        if (i < NB) { bucket_base[i] = base; base += v[j]; }
    }
    if (t == 255) { bucket_base[NB] = ts[255]; row_ptr[N] = ts[255]; }
}

__global__ __launch_bounds__(256) void bin_scatter_k(
    const int* __restrict__ e32, const long long* __restrict__ e64,
    const int* __restrict__ bh_ex, const int* __restrict__ bucket_base,
    int* __restrict__ pairs, int E, int NB, int B1, int bshift, int chunk)
{
    __shared__ int ofs[512];
    __shared__ int cnt[512];
    __shared__ int sflag;
    const int tid = threadIdx.x;
    if (tid < 64) {
        unsigned long long b = __ballot(e32[2 * tid + 1] != 0);
        if (tid == 0) sflag = (b == 0ULL);
    }
    for (int b = tid; b < NB; b += 256) {
        ofs[b] = bucket_base[b] + bh_ex[(size_t)b * B1 + blockIdx.x];
        cnt[b] = 0;
    }
    __syncthreads();
    const bool i64f = (sflag != 0);
    const int base = blockIdx.x * chunk;
    const int end  = min(base + chunk, E);
    const int mask = (1 << bshift) - 1;
    for (int i = base + tid; i < end; i += 256) {
        int s, d;
        if (i64f) { s = (int)e64[i]; d = (int)e64[(size_t)E + i]; }
        else      { s = e32[i];      d = e32[(size_t)E + i]; }
        int b = d >> bshift;
        int r = atomicAdd(&cnt[b], 1);
        pairs[ofs[b] + r] = (s << bshift) | (d & mask);
    }
}

__global__ __launch_bounds__(256) void buildcsr_k(
    const int* __restrict__ pairs, const int* __restrict__ bucket_base,
    int* __restrict__ row_ptr, int* __restrict__ csr, int N, int bshift)
{
    __shared__ int nh[256], sc[256], cur[256];
    const int t = threadIdx.x, b = blockIdx.x;
    const int n0 = b << bshift;
    const int nn = min(1 << bshift, N - n0);
    const int start = bucket_base[b], end = bucket_base[b + 1];
    const int mask = (1 << bshift) - 1;
    nh[t] = 0;
    __syncthreads();
    for (int i = start + t; i < end; i += 256)
        atomicAdd(&nh[pairs[i] & mask], 1);
    __syncthreads();
    sc[t] = nh[t];
    __syncthreads();
    for (int off = 1; off < 256; off <<= 1) {
        int y = (t >= off) ? sc[t - off] : 0;
        __syncthreads();
        sc[t] += y;
        __syncthreads();
    }
    if (t < nn) {
        int rp = start + sc[t] - nh[t];
        row_ptr[n0 + t] = rp;
        cur[t] = rp;
    }
    __syncthreads();
    for (int i = start + t; i < end; i += 256) {
        int p = pairs[i];
        int pos = atomicAdd(&cur[p & mask], 1);
        csr[pos] = p >> bshift;
    }
}

// ============ fused dual-GEMM via MFMA: [rows x 64] @ [64 x 128] bf16 ============
template<int MODE>
__global__ __launch_bounds__(256) void transform_mfma_k(
    const void* __restrict__ inv, const float* __restrict__ Wrel,
    const float* __restrict__ Wroot, const float* __restrict__ bias,
    __hip_bfloat16* __restrict__ outRel, __hip_bfloat16* __restrict__ outRoot,
    int nrows)
{
    const int tid = threadIdx.x;
    const int w = tid >> 6, l = tid & 63;
    const int rowHalf = w & 1, colHalf = w >> 1;
    const int lr = l & 15, lg = l >> 4;

    bf16x8 Bf[4][2];
    float bval[4];
#pragma unroll
    for (int jt = 0; jt < 4; ++jt) {
        int col = colHalf * 64 + jt * 16 + lr;
        const float* wrow = (col < 64) ? (Wrel + (size_t)col * 64)
                                       : (Wroot + (size_t)(col - 64) * 64);
#pragma unroll
        for (int kb = 0; kb < 2; ++kb) {
            const float4* p = (const float4*)(wrow + kb * 32 + lg * 8);
            float4 a = p[0], b = p[1];
            bf16x8 v;
            v[0] = (__bf16)a.x; v[1] = (__bf16)a.y; v[2] = (__bf16)a.z; v[3] = (__bf16)a.w;
            v[4] = (__bf16)b.x; v[5] = (__bf16)b.y; v[6] = (__bf16)b.z; v[7] = (__bf16)b.w;
            Bf[jt][kb] = v;
        }
        bval[jt] = (col >= 64) ? bias[col - 64] : 0.f;
    }

    for (int tile = blockIdx.x * 32; tile < nrows; tile += gridDim.x * 32) {
        int arow = tile + rowHalf * 16 + lr;
        int crow = min(arow, nrows - 1);
        bf16x8 Af[2];
#pragma unroll
        for (int kb = 0; kb < 2; ++kb) {
            float xv[8];
            if (MODE == 0) {
                const float4* p = (const float4*)((const float*)inv + (size_t)crow * 64 + kb * 32 + lg * 8);
                float4 a = p[0], b = p[1];
                xv[0]=a.x; xv[1]=a.y; xv[2]=a.z; xv[3]=a.w;
                xv[4]=b.x; xv[5]=b.y; xv[6]=b.z; xv[7]=b.w;
            } else {
                const ushort4* p = (const ushort4*)((const unsigned short*)inv + (size_t)crow * 64 + kb * 32 + lg * 8);
                ushort4 a = p[0], b = p[1];
                xv[0]=__uint_as_float((unsigned)a.x<<16); xv[1]=__uint_as_float((unsigned)a.y<<16);
                xv[2]=__uint_as_float((unsigned)a.z<<16); xv[3]=__uint_as_float((unsigned)a.w<<16);
                xv[4]=__uint_as_float((unsigned)b.x<<16); xv[5]=__uint_as_float((unsigned)b.y<<16);
                xv[6]=__uint_as_float((unsigned)b.z<<16); xv[7]=__uint_as_float((unsigned)b.w<<16);
#pragma unroll
                for (int e = 0; e < 8; ++e) xv[e] = fmaxf(xv[e], 0.f);
            }
            bf16x8 v;
#pragma unroll
            for (int e = 0; e < 8; ++e) v[e] = (__bf16)xv[e];
            Af[kb] = v;
        }

        f32x4 acc[4];
#pragma unroll
        for (int jt = 0; jt < 4; ++jt) {
            acc[jt][0] = 0.f; acc[jt][1] = 0.f; acc[jt][2] = 0.f; acc[jt][3] = 0.f;
#pragma unroll
            for (int kb = 0; kb < 2; ++kb)
                acc[jt] = __builtin_amdgcn_mfma_f32_16x16x32_bf16(Af[kb], Bf[jt][kb], acc[jt], 0, 0, 0);
        }

#pragma unroll
        for (int jt = 0; jt < 4; ++jt) {
            int col = colHalf * 64 + jt * 16 + lr;
#pragma unroll
            for (int r = 0; r < 4; ++r) {
                int row = tile + rowHalf * 16 + lg * 4 + r;
                if (row < nrows) {
                    float v = acc[jt][r];
                    if (col < 64)
                        outRel[(size_t)row * 64 + col] = __float2bfloat16(v);
                    else
                        outRoot[(size_t)row * 64 + (col - 64)] = __float2bfloat16(v + bval[jt]);
                }
            }
        }
    }
}

// ============ CSR gather-aggregate, paired-edge (2 edges per wave-load) ============
// lanes 0-31: edge e, channels (2hl,2hl+1); lanes 32-63: edge e+1. Combine via shfl_xor(32).
// FUSE_FC=1: compute out[n] = relu(h).Wfc + bfc directly, skip h write.
__device__ __forceinline__ float bft(unsigned short u) {
    return __uint_as_float((unsigned)u << 16);
}

template<int FUSE_FC>
__global__ __launch_bounds__(256) void agg2_k(
    const int* __restrict__ row_ptr, const int* __restrict__ csr,
    const unsigned short* __restrict__ rel, unsigned short* __restrict__ accb,
    const float* __restrict__ Wfc, const float* __restrict__ bfc,
    float* __restrict__ out, int N)
{
    int node = blockIdx.x * 4 + (threadIdx.x >> 6);
    if (node >= N) return;
    const int l = threadIdx.x & 63;
    const int half = l >> 5, hl = l & 31;

    int start = row_ptr[node];
    int end   = row_ptr[node + 1];

    float ax = 0.f, ay = 0.f;
    if (half == 0) {
        unsigned r = __builtin_nontemporal_load(
            (const unsigned*)(accb + (size_t)node * 64 + 2 * hl));
        ax = __uint_as_float((r & 0xFFFFu) << 16);
        ay = __uint_as_float(r & 0xFFFF0000u);
    }

    int e = start;
    for (; e + 8 <= end; e += 8) {
        int s[8];
#pragma unroll
        for (int j = 0; j < 8; ++j) s[j] = __builtin_nontemporal_load(csr + e + j);
        ushort2 v[4];
#pragma unroll
        for (int j = 0; j < 4; ++j) {
            int src = (half == 0) ? s[2 * j] : s[2 * j + 1];
            v[j] = *(const ushort2*)(rel + (size_t)src * 64 + 2 * hl);
        }
#pragma unroll
        for (int j = 0; j < 4; ++j) { ax += bft(v[j].x); ay += bft(v[j].y); }
    }
    for (; e + 2 <= end; e += 2) {
        int s0 = __builtin_nontemporal_load(csr + e);
        int s1 = __builtin_nontemporal_load(csr + e + 1);
        int src = (half == 0) ? s0 : s1;
        ushort2 v = *(const ushort2*)(rel + (size_t)src * 64 + 2 * hl);
        ax += bft(v.x); ay += bft(v.y);
    }
    if (e < end) {
        int s0 = __builtin_nontemporal_load(csr + e);
        if (half == 0) {
            ushort2 v = *(const ushort2*)(rel + (size_t)s0 * 64 + 2 * hl);
            ax += bft(v.x); ay += bft(v.y);
        }
    }

    ax += __shfl_xor(ax, 32, 64);
    ay += __shfl_xor(ay, 32, 64);

    if (FUSE_FC) {
        float w0 = Wfc[2 * hl], w1 = Wfc[2 * hl + 1];
        float v = fmaxf(ax, 0.f) * w0 + fmaxf(ay, 0.f) * w1;
#pragma unroll
        for (int m = 16; m >= 1; m >>= 1) v += __shfl_xor(v, m, 64);
        if (l == 0) out[node] = v + bfc[0];
    } else {
        if (half == 0) {
            __hip_bfloat16 hx = __float2bfloat16(ax);
            __hip_bfloat16 hy = __float2bfloat16(ay);
            unsigned st = (unsigned)(*(unsigned short*)&hx)
                        | ((unsigned)(*(unsigned short*)&hy) << 16);
            __builtin_nontemporal_store(st, (unsigned*)(accb + (size_t)node * 64 + 2 * hl));
        }
    }
}

extern "C" void kernel_launch(void* const* d_in, const int* in_sizes, int n_in,
                              void* d_out, int out_size, void* d_ws, size_t ws_size,
                              hipStream_t stream) {
    const float* x       = (const float*)d_in[0];
    const int* e32       = (const int*)d_in[1];
    const long long* e64 = (const long long*)d_in[1];
    const float* W1_rel  = (const float*)d_in[2];
    const float* W1_root = (const float*)d_in[3];
    const float* b1      = (const float*)d_in[4];
    const float* W2_rel  = (const float*)d_in[5];
    const float* W2_root = (const float*)d_in[6];
    const float* b2      = (const float*)d_in[7];
    const float* W_fc    = (const float*)d_in[8];
    const float* b_fc    = (const float*)d_in[9];
    float* out           = (float*)d_out;

    const int N = in_sizes[0] / 64;    // 100000
    const int E = in_sizes[1] / 2;     // 1600000

    const int bshift = 8;                                  // 256 nodes/bucket
    const int NB = (N + (1 << bshift) - 1) >> bshift;      // 391 (<=512)
    int chunk = 8192;
    while ((E + chunk - 1) / chunk > 256) chunk <<= 1;
    const int B1 = (E + chunk - 1) / chunk;                // 196

    // workspace (~52 MB)
    char* p = (char*)d_ws;
    unsigned short* bufA   = (unsigned short*)p; p += (size_t)N * 64 * 2;  // root1 / h1
    unsigned short* bufB   = (unsigned short*)p; p += (size_t)N * 64 * 2;  // root2
    unsigned short* bufRel = (unsigned short*)p; p += (size_t)N * 64 * 2;  // rel
    int* csr         = (int*)p;  p += (size_t)E * 4;
    int* pairs       = (int*)p;  p += (size_t)E * 4;
    int* row_ptr     = (int*)p;  p += (size_t)(N + 1) * 4;
    int* blockhist   = (int*)p;  p += (size_t)B1 * NB * 4;
    int* bh_ex       = (int*)p;  p += (size_t)NB * B1 * 4;
    int* btot        = (int*)p;  p += (size_t)NB * 4;
    int* bucket_base = (int*)p;

    // ---- CSR build ----
    bin_hist_k<<<B1, 256, 0, stream>>>(e32, e64, blockhist, E, NB, bshift, chunk);
    scanA_k<<<NB, 256, 0, stream>>>(blockhist, bh_ex, btot, NB, B1);
    scanB_k<<<1, 256, 0, stream>>>(btot, bucket_base, row_ptr, NB, N);
    bin_scatter_k<<<B1, 256, 0, stream>>>(e32, e64, bh_ex, bucket_base, pairs,
                                          E, NB, B1, bshift, chunk);
    buildcsr_k<<<NB, 256, 0, stream>>>(pairs, bucket_base, row_ptr, csr, N, bshift);

    // ---- layer 1 ----
    transform_mfma_k<0><<<1024, 256, 0, stream>>>(x, W1_rel, W1_root, b1,
        (__hip_bfloat16*)bufRel, (__hip_bfloat16*)bufA, N);
    agg2_k<0><<<(N + 3) / 4, 256, 0, stream>>>(row_ptr, csr, bufRel, bufA,
        nullptr, nullptr, nullptr, N);

    // ---- layer 2 (+ fused FC head) ----
    transform_mfma_k<1><<<1024, 256, 0, stream>>>(bufA, W2_rel, W2_root, b2,
        (__hip_bfloat16*)bufRel, (__hip_bfloat16*)bufB, N);
    agg2_k<1><<<(N + 3) / 4, 256, 0, stream>>>(row_ptr, csr, bufRel, bufB,
        W_fc, b_fc, out, N);
}

// Round 8
// 166.840 us; speedup vs baseline: 1.4585x; 1.4585x over previous
//
#include <hip/hip_runtime.h>
#include <hip/hip_bf16.h>

using bf16x8 = __attribute__((ext_vector_type(8))) __bf16;
using f32x4  = __attribute__((ext_vector_type(4))) float;

// ============ CSR build (deterministic two-level binning, bshift=8) ============
__global__ __launch_bounds__(256) void bin_hist_k(
    const int* __restrict__ e32, const long long* __restrict__ e64,
    int* __restrict__ blockhist /*[B1][NB]*/, int E, int NB, int bshift, int chunk)
{
    __shared__ int hist[512];
    __shared__ int sflag;
    const int tid = threadIdx.x;
    if (tid < 64) {
        unsigned long long b = __ballot(e32[2 * tid + 1] != 0);
        if (tid == 0) sflag = (b == 0ULL);
    }
    for (int i = tid; i < NB; i += 256) hist[i] = 0;
    __syncthreads();
    const bool i64f = (sflag != 0);
    const int base = blockIdx.x * chunk;
    const int end  = min(base + chunk, E);
    for (int i = base + tid; i < end; i += 256) {
        int d = i64f ? (int)e64[(size_t)E + i] : e32[(size_t)E + i];
        atomicAdd(&hist[d >> bshift], 1);
    }
    __syncthreads();
    int* row = blockhist + (size_t)blockIdx.x * NB;
    for (int b = tid; b < NB; b += 256) row[b] = hist[b];
}

__global__ __launch_bounds__(256) void scanA_k(
    const int* __restrict__ blockhist, int* __restrict__ bh_ex /*[NB][B1]*/,
    int* __restrict__ btot, int NB, int B1)
{
    __shared__ int v[256];
    const int t = threadIdx.x, b = blockIdx.x;
    int x = (t < B1) ? blockhist[(size_t)t * NB + b] : 0;
    v[t] = x; __syncthreads();
    for (int off = 1; off < 256; off <<= 1) {
        int y = (t >= off) ? v[t - off] : 0;
        __syncthreads();
        v[t] += y;
        __syncthreads();
    }
    if (t < B1) bh_ex[(size_t)b * B1 + t] = v[t] - x;
    if (t == 255) btot[b] = v[255];
}

__global__ __launch_bounds__(256) void scanB_k(
    const int* __restrict__ btot, int* __restrict__ bucket_base,
    int* __restrict__ row_ptr, int NB, int N)
{
    __shared__ int ts[256];
    const int t = threadIdx.x;
    int v[4], s = 0;
#pragma unroll
    for (int j = 0; j < 4; ++j) { int i = t * 4 + j; v[j] = (i < NB) ? btot[i] : 0; s += v[j]; }
    ts[t] = s; __syncthreads();
    for (int off = 1; off < 256; off <<= 1) {
        int x = (t >= off) ? ts[t - off] : 0;
        __syncthreads();
        ts[t] += x;
        __syncthreads();
    }
    int base = ts[t] - s;
#pragma unroll
    for (int j = 0; j < 4; ++j) {
        int i = t * 4 + j;
        if (i < NB) { bucket_base[i] = base; base += v[j]; }
    }
    if (t == 255) { bucket_base[NB] = ts[255]; row_ptr[N] = ts[255]; }
}

__global__ __launch_bounds__(256) void bin_scatter_k(
    const int* __restrict__ e32, const long long* __restrict__ e64,
    const int* __restrict__ bh_ex, const int* __restrict__ bucket_base,
    int* __restrict__ pairs, int E, int NB, int B1, int bshift, int chunk)
{
    __shared__ int ofs[512];
    __shared__ int cnt[512];
    __shared__ int sflag;
    const int tid = threadIdx.x;
    if (tid < 64) {
        unsigned long long b = __ballot(e32[2 * tid + 1] != 0);
        if (tid == 0) sflag = (b == 0ULL);
    }
    for (int b = tid; b < NB; b += 256) {
        ofs[b] = bucket_base[b] + bh_ex[(size_t)b * B1 + blockIdx.x];
        cnt[b] = 0;
    }
    __syncthreads();
    const bool i64f = (sflag != 0);
    const int base = blockIdx.x * chunk;
    const int end  = min(base + chunk, E);
    const int mask = (1 << bshift) - 1;
    for (int i = base + tid; i < end; i += 256) {
        int s, d;
        if (i64f) { s = (int)e64[i]; d = (int)e64[(size_t)E + i]; }
        else      { s = e32[i];      d = e32[(size_t)E + i]; }
        int b = d >> bshift;
        int r = atomicAdd(&cnt[b], 1);
        pairs[ofs[b] + r] = (s << bshift) | (d & mask);
    }
}

__global__ __launch_bounds__(256) void buildcsr_k(
    const int* __restrict__ pairs, const int* __restrict__ bucket_base,
    int* __restrict__ row_ptr, int* __restrict__ csr, int N, int bshift)
{
    __shared__ int nh[256], sc[256], cur[256];
    const int t = threadIdx.x, b = blockIdx.x;
    const int n0 = b << bshift;
    const int nn = min(1 << bshift, N - n0);
    const int start = bucket_base[b], end = bucket_base[b + 1];
    const int mask = (1 << bshift) - 1;
    nh[t] = 0;
    __syncthreads();
    for (int i = start + t; i < end; i += 256)
        atomicAdd(&nh[pairs[i] & mask], 1);
    __syncthreads();
    sc[t] = nh[t];
    __syncthreads();
    for (int off = 1; off < 256; off <<= 1) {
        int y = (t >= off) ? sc[t - off] : 0;
        __syncthreads();
        sc[t] += y;
        __syncthreads();
    }
    if (t < nn) {
        int rp = start + sc[t] - nh[t];
        row_ptr[n0 + t] = rp;
        cur[t] = rp;
    }
    __syncthreads();
    for (int i = start + t; i < end; i += 256) {
        int p = pairs[i];
        int pos = atomicAdd(&cur[p & mask], 1);
        csr[pos] = p >> bshift;
    }
}

// ============ fused dual-GEMM via MFMA: [rows x 64] @ [64 x 128] bf16 ============
template<int MODE>
__global__ __launch_bounds__(256) void transform_mfma_k(
    const void* __restrict__ inv, const float* __restrict__ Wrel,
    const float* __restrict__ Wroot, const float* __restrict__ bias,
    __hip_bfloat16* __restrict__ outRel, __hip_bfloat16* __restrict__ outRoot,
    int nrows)
{
    const int tid = threadIdx.x;
    const int w = tid >> 6, l = tid & 63;
    const int rowHalf = w & 1, colHalf = w >> 1;
    const int lr = l & 15, lg = l >> 4;

    bf16x8 Bf[4][2];
    float bval[4];
#pragma unroll
    for (int jt = 0; jt < 4; ++jt) {
        int col = colHalf * 64 + jt * 16 + lr;
        const float* wrow = (col < 64) ? (Wrel + (size_t)col * 64)
                                       : (Wroot + (size_t)(col - 64) * 64);
#pragma unroll
        for (int kb = 0; kb < 2; ++kb) {
            const float4* p = (const float4*)(wrow + kb * 32 + lg * 8);
            float4 a = p[0], b = p[1];
            bf16x8 v;
            v[0] = (__bf16)a.x; v[1] = (__bf16)a.y; v[2] = (__bf16)a.z; v[3] = (__bf16)a.w;
            v[4] = (__bf16)b.x; v[5] = (__bf16)b.y; v[6] = (__bf16)b.z; v[7] = (__bf16)b.w;
            Bf[jt][kb] = v;
        }
        bval[jt] = (col >= 64) ? bias[col - 64] : 0.f;
    }

    for (int tile = blockIdx.x * 32; tile < nrows; tile += gridDim.x * 32) {
        int arow = tile + rowHalf * 16 + lr;
        int crow = min(arow, nrows - 1);
        bf16x8 Af[2];
#pragma unroll
        for (int kb = 0; kb < 2; ++kb) {
            float xv[8];
            if (MODE == 0) {
                const float4* p = (const float4*)((const float*)inv + (size_t)crow * 64 + kb * 32 + lg * 8);
                float4 a = p[0], b = p[1];
                xv[0]=a.x; xv[1]=a.y; xv[2]=a.z; xv[3]=a.w;
                xv[4]=b.x; xv[5]=b.y; xv[6]=b.z; xv[7]=b.w;
            } else {
                const ushort4* p = (const ushort4*)((const unsigned short*)inv + (size_t)crow * 64 + kb * 32 + lg * 8);
                ushort4 a = p[0], b = p[1];
                xv[0]=__uint_as_float((unsigned)a.x<<16); xv[1]=__uint_as_float((unsigned)a.y<<16);
                xv[2]=__uint_as_float((unsigned)a.z<<16); xv[3]=__uint_as_float((unsigned)a.w<<16);
                xv[4]=__uint_as_float((unsigned)b.x<<16); xv[5]=__uint_as_float((unsigned)b.y<<16);
                xv[6]=__uint_as_float((unsigned)b.z<<16); xv[7]=__uint_as_float((unsigned)b.w<<16);
#pragma unroll
                for (int e = 0; e < 8; ++e) xv[e] = fmaxf(xv[e], 0.f);
            }
            bf16x8 v;
#pragma unroll
            for (int e = 0; e < 8; ++e) v[e] = (__bf16)xv[e];
            Af[kb] = v;
        }

        f32x4 acc[4];
#pragma unroll
        for (int jt = 0; jt < 4; ++jt) {
            acc[jt][0] = 0.f; acc[jt][1] = 0.f; acc[jt][2] = 0.f; acc[jt][3] = 0.f;
#pragma unroll
            for (int kb = 0; kb < 2; ++kb)
                acc[jt] = __builtin_amdgcn_mfma_f32_16x16x32_bf16(Af[kb], Bf[jt][kb], acc[jt], 0, 0, 0);
        }

#pragma unroll
        for (int jt = 0; jt < 4; ++jt) {
            int col = colHalf * 64 + jt * 16 + lr;
#pragma unroll
            for (int r = 0; r < 4; ++r) {
                int row = tile + rowHalf * 16 + lg * 4 + r;
                if (row < nrows) {
                    float v = acc[jt][r];
                    if (col < 64)
                        outRel[(size_t)row * 64 + col] = __float2bfloat16(v);
                    else
                        outRoot[(size_t)row * 64 + (col - 64)] = __float2bfloat16(v + bval[jt]);
                }
            }
        }
    }
}

// ============ CSR gather-aggregate, lane-per-channel, 8-deep MLP ============
// One wave per node; lane = channel. 8 independent gathers in flight; tail is a
// clamped predicated 8-block (no serial dependent tail).
// FUSE_FC=1: out[n] = relu(acc).Wfc + bfc via ds_swizzle butterfly + readlane(32).
__device__ __forceinline__ float bft(unsigned short u) {
    return __uint_as_float((unsigned)u << 16);
}

template<int FUSE_FC>
__global__ __launch_bounds__(256) void agg3_k(
    const int* __restrict__ row_ptr, const int* __restrict__ csr,
    const unsigned short* __restrict__ rel, unsigned short* __restrict__ accb,
    const float* __restrict__ Wfc, const float* __restrict__ bfc,
    float* __restrict__ out, int N)
{
    const int wid  = __builtin_amdgcn_readfirstlane(threadIdx.x >> 6);
    const int lane = threadIdx.x & 63;
    const int node = blockIdx.x * 4 + wid;
    if (node >= N) return;

    const int start = row_ptr[node];
    const int end   = row_ptr[node + 1];

    float acc = bft(accb[(size_t)node * 64 + lane]);   // root term

    int e = start;
    for (; e + 8 <= end; e += 8) {
        int s[8];
#pragma unroll
        for (int j = 0; j < 8; ++j) s[j] = csr[e + j];
        float v[8];
#pragma unroll
        for (int j = 0; j < 8; ++j) v[j] = bft(rel[(size_t)s[j] * 64 + lane]);
#pragma unroll
        for (int j = 0; j < 8; ++j) acc += v[j];
    }
    int r = end - e;
    if (r > 0) {
        int s[8];
#pragma unroll
        for (int j = 0; j < 8; ++j) s[j] = csr[e + min(j, r - 1)];  // clamped: always valid
        float v[8];
#pragma unroll
        for (int j = 0; j < 8; ++j) v[j] = bft(rel[(size_t)s[j] * 64 + lane]);
#pragma unroll
        for (int j = 0; j < 8; ++j) acc += (j < r) ? v[j] : 0.f;
    }

    if (FUSE_FC) {
        float v = fmaxf(acc, 0.f) * Wfc[lane];
        // butterfly within 32-lane groups: xor 1,2,4,8,16 (BitMode, and=0x1F)
        v += __int_as_float(__builtin_amdgcn_ds_swizzle(__float_as_int(v), 0x041F));
        v += __int_as_float(__builtin_amdgcn_ds_swizzle(__float_as_int(v), 0x081F));
        v += __int_as_float(__builtin_amdgcn_ds_swizzle(__float_as_int(v), 0x101F));
        v += __int_as_float(__builtin_amdgcn_ds_swizzle(__float_as_int(v), 0x201F));
        v += __int_as_float(__builtin_amdgcn_ds_swizzle(__float_as_int(v), 0x401F));
        float hi = __int_as_float(__builtin_amdgcn_readlane(__float_as_int(v), 32));
        if (lane == 0) out[node] = v + hi + bfc[0];
    } else {
        __hip_bfloat16 hb = __float2bfloat16(acc);
        accb[(size_t)node * 64 + lane] = *(unsigned short*)&hb;
    }
}

extern "C" void kernel_launch(void* const* d_in, const int* in_sizes, int n_in,
                              void* d_out, int out_size, void* d_ws, size_t ws_size,
                              hipStream_t stream) {
    const float* x       = (const float*)d_in[0];
    const int* e32       = (const int*)d_in[1];
    const long long* e64 = (const long long*)d_in[1];
    const float* W1_rel  = (const float*)d_in[2];
    const float* W1_root = (const float*)d_in[3];
    const float* b1      = (const float*)d_in[4];
    const float* W2_rel  = (const float*)d_in[5];
    const float* W2_root = (const float*)d_in[6];
    const float* b2      = (const float*)d_in[7];
    const float* W_fc    = (const float*)d_in[8];
    const float* b_fc    = (const float*)d_in[9];
    float* out           = (float*)d_out;

    const int N = in_sizes[0] / 64;    // 100000
    const int E = in_sizes[1] / 2;     // 1600000

    const int bshift = 8;                                  // 256 nodes/bucket
    const int NB = (N + (1 << bshift) - 1) >> bshift;      // 391 (<=512)
    int chunk = 8192;
    while ((E + chunk - 1) / chunk > 256) chunk <<= 1;
    const int B1 = (E + chunk - 1) / chunk;                // 196

    // workspace (~52 MB)
    char* p = (char*)d_ws;
    unsigned short* bufA   = (unsigned short*)p; p += (size_t)N * 64 * 2;  // root1 / h1
    unsigned short* bufB   = (unsigned short*)p; p += (size_t)N * 64 * 2;  // root2
    unsigned short* bufRel = (unsigned short*)p; p += (size_t)N * 64 * 2;  // rel
    int* csr         = (int*)p;  p += (size_t)E * 4;
    int* pairs       = (int*)p;  p += (size_t)E * 4;
    int* row_ptr     = (int*)p;  p += (size_t)(N + 1) * 4;
    int* blockhist   = (int*)p;  p += (size_t)B1 * NB * 4;
    int* bh_ex       = (int*)p;  p += (size_t)NB * B1 * 4;
    int* btot        = (int*)p;  p += (size_t)NB * 4;
    int* bucket_base = (int*)p;

    // ---- CSR build ----
    bin_hist_k<<<B1, 256, 0, stream>>>(e32, e64, blockhist, E, NB, bshift, chunk);
    scanA_k<<<NB, 256, 0, stream>>>(blockhist, bh_ex, btot, NB, B1);
    scanB_k<<<1, 256, 0, stream>>>(btot, bucket_base, row_ptr, NB, N);
    bin_scatter_k<<<B1, 256, 0, stream>>>(e32, e64, bh_ex, bucket_base, pairs,
                                          E, NB, B1, bshift, chunk);
    buildcsr_k<<<NB, 256, 0, stream>>>(pairs, bucket_base, row_ptr, csr, N, bshift);

    // ---- layer 1 ----
    transform_mfma_k<0><<<1024, 256, 0, stream>>>(x, W1_rel, W1_root, b1,
        (__hip_bfloat16*)bufRel, (__hip_bfloat16*)bufA, N);
    agg3_k<0><<<(N + 3) / 4, 256, 0, stream>>>(row_ptr, csr, bufRel, bufA,
        nullptr, nullptr, nullptr, N);

    // ---- layer 2 (+ fused FC head) ----
    transform_mfma_k<1><<<1024, 256, 0, stream>>>(bufA, W2_rel, W2_root, b2,
        (__hip_bfloat16*)bufRel, (__hip_bfloat16*)bufB, N);
    agg3_k<1><<<(N + 3) / 4, 256, 0, stream>>>(row_ptr, csr, bufRel, bufB,
        W_fc, b_fc, out, N);
}